// Round 3
// baseline (646.218 us; speedup 1.0000x reference)
//
#include <hip/hip_runtime.h>

// LSTM (B=2048, T=1024, I=8, H=64) + sigmoid(FC), bf16 MFMA, in-register
// activations, duplicate-column split — DUAL-CHAIN revision.
//
// R=8 batch rows/block -> 256 blocks = 1/CU. Each wave runs TWO independent
// LSTM chains (set P = rows 0-3, set Q = rows 4-7) sharing the same A
// (weight) fragments. The two chains interleave statically in the
// instruction stream, so each chain's ds_read/exp latency hides under the
// other — replacing the unreliable 2-block phase overlap of the R=4 kernel.
// Per step per wave: 6 ds_read_b128 -> 24 MFMA -> 2 activation chains ->
// 2 ds_write_b16 -> one 4-wave barrier.
//
// Kept r0-exact idioms (the 476us configuration): __expf-based activations
// (native v_exp; exp2f lowers to precise ocml w/ fixup code — measured +22%
// VALU cycles in r1/r2), manual f2bf, plain __syncthreads, no unroll
// pragmas, no inline asm. HP=80 kept (bank conflicts 1.88e7->2.0e6,
// verified neutral-to-good).

namespace {
constexpr int T_LEN = 1024;
constexpr int R     = 8;    // batch rows per block (two sets of 4)
constexpr int TS    = 32;   // timesteps of x per staged chunk
constexpr int HP    = 80;   // h_lds row stride in shorts (160 B, 16B-aligned)

typedef __attribute__((ext_vector_type(8))) short  short8v;
typedef __attribute__((ext_vector_type(4))) float  float4v;
typedef unsigned short u16;
typedef unsigned long long u64;

__device__ __forceinline__ float fsig(float x) {
  return __builtin_amdgcn_rcpf(1.f + __expf(-x));
}
__device__ __forceinline__ float ftanh(float x) {
  return 1.f - 2.f * __builtin_amdgcn_rcpf(__expf(2.f * x) + 1.f);
}
__device__ __forceinline__ u16 f2bf(float f) {  // RNE
  unsigned int u = __float_as_uint(f);
  unsigned int r = ((u >> 16) & 1u) + 0x7fffu;
  return (u16)((u + r) >> 16);
}

__global__ __launch_bounds__(256, 1) void lstm_dual(
    const float* __restrict__ x,     // [B, T, 8]
    const float* __restrict__ W_ih,  // [256, 8]
    const float* __restrict__ W_hh,  // [256, 64]
    const float* __restrict__ b_ih,  // [256]
    const float* __restrict__ b_hh,  // [256]
    const float* __restrict__ fc_w,  // [64]
    const float* __restrict__ fc_b,  // [1]
    float* __restrict__ out) {       // [B]
  __shared__ __align__(16) u16   x_lds[2][TS][R][32];  // 32 KB; full K-rows
  __shared__ __align__(16) u16   h_lds[2][R][HP];      // 2.5 KB
  __shared__ __align__(16) float hf[R][64];            // final h (fp32)

  const int tid  = threadIdx.x;
  const int lane = tid & 63;
  const int wv   = tid >> 6;       // wave 0..3
  const int g4   = lane >> 4;      // MFMA k-quad / C row-quad
  const int nib  = lane & 15;      // MFMA m/n coord
  const int rowP = nib & 3;        // set P batch row (cols 4..15 duplicate)
  const int rowQ = 4 + rowP;       // set Q batch row
  const int rsel = nib >> 2;       // which acc reg this thread activates
  const int jh   = 16 * wv + 4 * g4 + rsel;  // owned h index
  const int bBase = blockIdx.x * R;

  // ---- static A fragments: wave wv holds tiles {4g+wv}, g=0..3 (i,f,g,o),
  //      shared by both chains ----
  short8v a0[4], a1[4], a2[4];
  for (int g = 0; g < 4; ++g) {
    const int n = 64 * g + 16 * wv + nib;  // gate row
    short8v f0, f1, f2;
    for (int j = 0; j < 8; ++j) {
      const int k = 8 * g4 + j;
      float v0 = 0.f;
      if (k < 8) v0 = W_ih[n * 8 + k];
      else if (k == 8) v0 = b_ih[n] + b_hh[n];
      f0[j] = (short)f2bf(v0);
      f1[j] = (short)f2bf(W_hh[n * 64 + k]);
      f2[j] = (short)f2bf(W_hh[n * 64 + 32 + k]);
    }
    a0[g] = f0; a1[g] = f1; a2[g] = f2;
  }

  // ---- LDS init: h0 = 0 (both bufs); x constant channels once per buf ----
  for (int i = tid; i < 2 * R * HP; i += 256) ((u16*)h_lds)[i] = 0;
  for (int idx = tid; idx < 2 * TS * R; idx += 256) {
    const int buf = idx >> 8, rem = idx & 255, tt = rem >> 3, rr = rem & 7;
    u16* p = &x_lds[buf][tt][rr][0];
    p[8] = 0x3f80;  // bias channel = 1.0
    for (int chn = 9; chn < 32; ++chn) p[chn] = 0;
  }

  // ---- x staging: 2 float4/thread/chunk, double-buffered ----
  // per chunk: 8 rows x 32 tt x 8 ch x 4B = 8 KB; 256 threads x 32 B.
  float4v xrA, xrB;
  const int sr = tid >> 5, sm = tid & 31;          // src row, float4 idx base
  const int m1 = sm, m2 = sm + 32;
  const int tt1 = m1 >> 1, ch1 = (m1 & 1) * 4;
  const int tt2 = m2 >> 1, ch2 = (m2 & 1) * 4;
  auto stage_load = [&](int chunk) {
    const float* src = x + ((size_t)bBase + sr) * (T_LEN * 8) +
                       (size_t)chunk * (TS * 8);
    xrA = *(const float4v*)&src[m1 * 4];
    xrB = *(const float4v*)&src[m2 * 4];
  };
  auto stage_write = [&](int buf) {
    union { u64 u; u16 s[4]; } p;
    p.s[0] = f2bf(xrA[0]); p.s[1] = f2bf(xrA[1]);
    p.s[2] = f2bf(xrA[2]); p.s[3] = f2bf(xrA[3]);
    *(u64*)&x_lds[buf][tt1][sr][ch1] = p.u;
    p.s[0] = f2bf(xrB[0]); p.s[1] = f2bf(xrB[1]);
    p.s[2] = f2bf(xrB[2]); p.s[3] = f2bf(xrB[3]);
    *(u64*)&x_lds[buf][tt2][sr][ch2] = p.u;
  };

  stage_load(0);
  stage_write(0);
  __syncthreads();

  // hoisted select masks for the cndmask tree
  const bool sel1 = (rsel & 1) != 0;
  const bool sel2 = (rsel & 2) != 0;
  float cP = 0.f, cQ = 0.f;

  for (int ch = 0; ch < T_LEN / TS; ++ch) {
    const int xb = ch & 1;
    const bool more = (ch < T_LEN / TS - 1);
    for (int tt = 0; tt < TS; ++tt) {
      const int t = ch * TS + tt;
      const int hb = t & 1;
      if (tt == 0 && more) stage_load(ch + 1);  // reg loads; drain in stage_write

      // ---- B fragments (uniform b128 reads), both chains ----
      const short8v fxP  = *(const short8v*)&x_lds[xb][tt][rowP][8 * g4];
      const short8v fxQ  = *(const short8v*)&x_lds[xb][tt][rowQ][8 * g4];
      const short8v fh0P = *(const short8v*)&h_lds[hb][rowP][8 * g4];
      const short8v fh1P = *(const short8v*)&h_lds[hb][rowP][32 + 8 * g4];
      const short8v fh0Q = *(const short8v*)&h_lds[hb][rowQ][8 * g4];
      const short8v fh1Q = *(const short8v*)&h_lds[hb][rowQ][32 + 8 * g4];

      // ---- 24 MFMAs: 4 gate-quads x (x | h-lo | h-hi) x 2 chains ----
      float4v accP[4], accQ[4];
#pragma unroll
      for (int g = 0; g < 4; ++g) {
        accP[g] = __builtin_amdgcn_mfma_f32_16x16x32_bf16(
            a0[g], fxP, (float4v){0.f, 0.f, 0.f, 0.f}, 0, 0, 0);
        accQ[g] = __builtin_amdgcn_mfma_f32_16x16x32_bf16(
            a0[g], fxQ, (float4v){0.f, 0.f, 0.f, 0.f}, 0, 0, 0);
      }
#pragma unroll
      for (int g = 0; g < 4; ++g) {
        accP[g] = __builtin_amdgcn_mfma_f32_16x16x32_bf16(a1[g], fh0P, accP[g], 0, 0, 0);
        accQ[g] = __builtin_amdgcn_mfma_f32_16x16x32_bf16(a1[g], fh0Q, accQ[g], 0, 0, 0);
      }
#pragma unroll
      for (int g = 0; g < 4; ++g) {
        accP[g] = __builtin_amdgcn_mfma_f32_16x16x32_bf16(a2[g], fh1P, accP[g], 0, 0, 0);
        accQ[g] = __builtin_amdgcn_mfma_f32_16x16x32_bf16(a2[g], fh1Q, accQ[g], 0, 0, 0);
      }

      // ---- pick this thread's elements (reg-select trees) ----
      float gsP[4], gsQ[4];
#pragma unroll
      for (int g = 0; g < 4; ++g) {
        const float p01 = sel1 ? accP[g][1] : accP[g][0];
        const float p23 = sel1 ? accP[g][3] : accP[g][2];
        gsP[g] = sel2 ? p23 : p01;
        const float q01 = sel1 ? accQ[g][1] : accQ[g][0];
        const float q23 = sel1 ? accQ[g][3] : accQ[g][2];
        gsQ[g] = sel2 ? q23 : q01;
      }

      // ---- activate both chains (independent; interleave hides exp latency)
      const float iP = fsig(gsP[0]), iQ = fsig(gsQ[0]);
      const float fP = fsig(gsP[1]), fQ = fsig(gsQ[1]);
      const float gP = ftanh(gsP[2]), gQ = ftanh(gsQ[2]);
      const float oP = fsig(gsP[3]), oQ = fsig(gsQ[3]);
      cP = fP * cP + iP * gP;
      cQ = fQ * cQ + iQ * gQ;
      const float hP = oP * ftanh(cP);
      const float hQ = oQ * ftanh(cQ);
      h_lds[hb ^ 1][rowP][jh] = f2bf(hP);
      h_lds[hb ^ 1][rowQ][jh] = f2bf(hQ);
      if (t == T_LEN - 1) { hf[rowP][jh] = hP; hf[rowQ][jh] = hQ; }
      if (tt == TS - 1 && more) stage_write((ch + 1) & 1);
      __syncthreads();  // one 4-wave barrier per step
    }
  }

  // ---- epilogue: out[b] = sigmoid(hT . fc_w + fc_b) ----
  if (tid < R) {
    float a = fc_b[0];
#pragma unroll
    for (int k = 0; k < 64; ++k) a += hf[tid][k] * fc_w[k];
    out[bBase + tid] = fsig(a);
  }
}
}  // namespace

extern "C" void kernel_launch(void* const* d_in, const int* in_sizes, int n_in,
                              void* d_out, int out_size, void* d_ws,
                              size_t ws_size, hipStream_t stream) {
  const float* x    = (const float*)d_in[0];
  const float* W_ih = (const float*)d_in[1];
  const float* W_hh = (const float*)d_in[2];
  const float* b_ih = (const float*)d_in[3];
  const float* b_hh = (const float*)d_in[4];
  const float* fc_w = (const float*)d_in[5];
  const float* fc_b = (const float*)d_in[6];
  float* out = (float*)d_out;

  const int B = in_sizes[0] / (T_LEN * 8);  // 2048
  lstm_dual<<<dim3(B / R), dim3(256), 0, stream>>>(x, W_ih, W_hh, b_ih, b_hh,
                                                   fc_w, fc_b, out);
}